// Round 4
// baseline (1593.759 us; speedup 1.0000x reference)
//
#include <hip/hip_runtime.h>

#define D 64

// ---- bf16 helpers ----
static __device__ __forceinline__ unsigned short f2bf(float f) {
    unsigned int u = __float_as_uint(f);
    unsigned int r = (u + 0x7FFFu + ((u >> 16) & 1u)) >> 16;
    return (unsigned short)r;
}
static __device__ __forceinline__ float bflo(unsigned int u) {
    return __uint_as_float(u << 16);
}
static __device__ __forceinline__ float bfhi(unsigned int u) {
    return __uint_as_float(u & 0xFFFF0000u);
}

// ---------------- init: fp32 acc + bf16 cur ----------------
__global__ void init_kernel(const float4* __restrict__ user_w,
                            const float4* __restrict__ item_w,
                            float4* __restrict__ acc,
                            ushort4* __restrict__ curb,
                            int n_user4, int n_tot4) {
    int i = blockIdx.x * blockDim.x + threadIdx.x;
    if (i >= n_tot4) return;
    float4 v = (i < n_user4) ? user_w[i] : item_w[i - n_user4];
    acc[i] = v;
    ushort4 b;
    b.x = f2bf(v.x); b.y = f2bf(v.y); b.z = f2bf(v.z); b.w = f2bf(v.w);
    curb[i] = b;
}

// ---------------- CSR build ----------------
// deg histogram + per-(slice,bucket) counts. MUST be launched with 256-thread
// blocks: slice = blockIdx&7 matches bucket_kernel's edge->slice mapping.
__global__ void hist_kernel(const int* __restrict__ dst, int* __restrict__ deg,
                            int* __restrict__ sb_cnt, int R_, int E_) {
    int i = blockIdx.x * 256 + threadIdx.x;
    if (i >= E_) return;
    int d = dst[i];
    atomicAdd(&deg[d], 1);
    atomicAdd(&sb_cnt[(blockIdx.x & 7) * R_ + (d >> 9)], 1);
}

// A: per-block partial sums of deg (block = 1024 elems)
__global__ void partial_kernel(const int* __restrict__ deg, int* __restrict__ partial, int N_) {
    __shared__ int sh[1024];
    int tid = threadIdx.x;
    int i = blockIdx.x * 1024 + tid;
    sh[tid] = (i < N_) ? deg[i] : 0;
    __syncthreads();
    for (int off = 512; off; off >>= 1) {
        if (tid < off) sh[tid] += sh[tid + off];
        __syncthreads();
    }
    if (tid == 0) partial[blockIdx.x] = sh[0];
}

// B: single block, exclusive scan of up to 1024 partials (in place)
__global__ void scan_partials_kernel(int* __restrict__ partial, int G_) {
    __shared__ int sh[1024];
    int tid = threadIdx.x;
    int v = (tid < G_) ? partial[tid] : 0;
    sh[tid] = v;
    __syncthreads();
    for (int off = 1; off < 1024; off <<= 1) {
        int t = (tid >= off) ? sh[tid - off] : 0;
        __syncthreads();
        sh[tid] += t;
        __syncthreads();
    }
    if (tid < G_) partial[tid] = sh[tid] - v;  // exclusive
}

// C: block-local scan + global offset -> row_ptr, cur_pos
__global__ void scan_write_kernel(const int* __restrict__ deg,
                                  const int* __restrict__ partial,
                                  int* __restrict__ row_ptr,
                                  int* __restrict__ cur_pos,
                                  int N_, int E_) {
    __shared__ int sh[1024];
    int tid = threadIdx.x;
    int i = blockIdx.x * 1024 + tid;
    int v = (i < N_) ? deg[i] : 0;
    sh[tid] = v;
    __syncthreads();
    for (int off = 1; off < 1024; off <<= 1) {
        int t = (tid >= off) ? sh[tid - off] : 0;
        __syncthreads();
        sh[tid] += t;
        __syncthreads();
    }
    if (i < N_) {
        int excl = sh[tid] - v + partial[blockIdx.x];
        row_ptr[i] = excl;
        cur_pos[i] = excl;
    }
    if (i == N_ - 1) row_ptr[N_] = E_;
}

// single block: exclusive scan of SR (<=8192) slice-bucket counts
__global__ void scan_sb_kernel(const int* __restrict__ cnt,
                               int* __restrict__ base,
                               int* __restrict__ pos, int SR) {
    __shared__ int sh[1024];
    int tid = threadIdx.x;
    int per = (SR + 1023) >> 10;
    int beg = tid * per;
    int end = min(beg + per, SR);
    int s = 0;
    for (int i = beg; i < end; ++i) s += cnt[i];
    sh[tid] = s;
    __syncthreads();
    for (int off = 1; off < 1024; off <<= 1) {
        int t = (tid >= off) ? sh[tid - off] : 0;
        __syncthreads();
        sh[tid] += t;
        __syncthreads();
    }
    int run = (tid > 0) ? sh[tid - 1] : 0;
    for (int i = beg; i < end; ++i) {
        base[i] = run;
        pos[i] = run;
        run += cnt[i];
    }
}

// pass 1: bin edges into (slice,bucket) append streams. 256-thread blocks:
// slice = blockIdx&7 ~ XCD (round-robin heuristic) -> single-XCD write streams.
__global__ void bucket_kernel(const int* __restrict__ src,
                              const int* __restrict__ dst,
                              const float* __restrict__ val,
                              int* __restrict__ sb_pos,
                              int* __restrict__ st_src,
                              int* __restrict__ st_dst,
                              float* __restrict__ st_val,
                              int R_, int E_) {
    int i = blockIdx.x * 256 + threadIdx.x;
    if (i >= E_) return;
    int d = dst[i];
    int t = atomicAdd(&sb_pos[(blockIdx.x & 7) * R_ + (d >> 9)], 1);
    st_src[t] = src[i];
    st_dst[t] = d;
    st_val[t] = val[i];
}

// pass 2: one block per bucket; scatter into this bucket's col_val span
// (~130KB, stays in one XCD L2 until done -> evicted once).
__global__ void place_kernel(const int* __restrict__ st_src,
                             const int* __restrict__ st_dst,
                             const float* __restrict__ st_val,
                             const int* __restrict__ sb_base,
                             const int* __restrict__ sb_cnt,
                             int* __restrict__ cur_pos,
                             int2* __restrict__ col_val, int R_) {
    int b = blockIdx.x;
    for (int s = 0; s < 8; ++s) {
        int beg = sb_base[s * R_ + b];
        int end = beg + sb_cnt[s * R_ + b];
        for (int e = beg + threadIdx.x; e < end; e += 512) {
            int d = st_dst[e];
            int p = atomicAdd(&cur_pos[d], 1);
            col_val[p] = make_int2(st_src[e], __float_as_int(st_val[e]));
        }
    }
}

// ---------------- CSR gather SpMM, bf16 rows, 16B/lane loads ----------------
// Wave per row; 8 lanes per gathered row (uint4 = 16B), 8 edges per iteration.
__global__ void spmm_csr_kernel(const int* __restrict__ row_ptr,
                                const int2* __restrict__ col_val,
                                const uint4* __restrict__ xb,
                                uint4* __restrict__ nxtb,
                                float4* __restrict__ acc,
                                int N_, int write_nxt) {
    int row = (int)((blockIdx.x * blockDim.x + threadIdx.x) >> 6);
    int lane = threadIdx.x & 63;
    if (row >= N_) return;
    int q = lane >> 3;    // which of 8 edges in the group
    int lid = lane & 7;   // which 16B chunk of the row
    int beg = row_ptr[row];
    int end = row_ptr[row + 1];
    float s0 = 0, s1 = 0, s2 = 0, s3 = 0, s4 = 0, s5 = 0, s6 = 0, s7 = 0;
    for (int base = beg; base < end; base += 64) {
        int e = base + lane;
        int c = 0;
        float v = 0.f;
        if (e < end) {
            int2 cv = col_val[e];
            c = cv.x;
            v = __int_as_float(cv.y);
        }
        int m = min(64, end - base);
        int m8 = (m + 7) & ~7;
        for (int j = 0; j < m8; j += 8) {
            int cj = __shfl(c, j + q, 64);
            float vj = __shfl(v, j + q, 64);
            uint4 t = xb[(long)cj * 8 + lid];
            s0 += vj * bflo(t.x); s1 += vj * bfhi(t.x);
            s2 += vj * bflo(t.y); s3 += vj * bfhi(t.y);
            s4 += vj * bflo(t.z); s5 += vj * bfhi(t.z);
            s6 += vj * bflo(t.w); s7 += vj * bfhi(t.w);
        }
    }
#pragma unroll
    for (int off = 32; off >= 8; off >>= 1) {
        s0 += __shfl_xor(s0, off, 64);
        s1 += __shfl_xor(s1, off, 64);
        s2 += __shfl_xor(s2, off, 64);
        s3 += __shfl_xor(s3, off, 64);
        s4 += __shfl_xor(s4, off, 64);
        s5 += __shfl_xor(s5, off, 64);
        s6 += __shfl_xor(s6, off, 64);
        s7 += __shfl_xor(s7, off, 64);
    }
    if (q == 0) {
        if (write_nxt) {
            uint4 b;
            b.x = (unsigned)f2bf(s0) | ((unsigned)f2bf(s1) << 16);
            b.y = (unsigned)f2bf(s2) | ((unsigned)f2bf(s3) << 16);
            b.z = (unsigned)f2bf(s4) | ((unsigned)f2bf(s5) << 16);
            b.w = (unsigned)f2bf(s6) | ((unsigned)f2bf(s7) << 16);
            nxtb[(long)row * 8 + lid] = b;
        }
        float4* ap = acc + (long)row * 16 + lid * 2;
        float4 a0 = ap[0];
        a0.x += s0; a0.y += s1; a0.z += s2; a0.w += s3;
        ap[0] = a0;
        float4 a1 = ap[1];
        a1.x += s4; a1.y += s5; a1.z += s6; a1.w += s7;
        ap[1] = a1;
    }
}

// ---------------- epilogue ----------------
__global__ void final_kernel(const float* __restrict__ acc,
                             const float* __restrict__ user_w,
                             const float* __restrict__ item_w,
                             const int* __restrict__ bu,
                             const int* __restrict__ bp,
                             const int* __restrict__ bn,
                             float* __restrict__ out,
                             int U_, int B_) {
    int w = (int)((blockIdx.x * blockDim.x + threadIdx.x) >> 6);
    int lane = threadIdx.x & 63;
    if (w >= B_) return;
    int iu = bu[w], ip = bp[w], in_ = bn[w];
    const float scale = 0.25f;  // 1/(L+1)
    float u = acc[(long)iu * D + lane] * scale;
    float p = acc[(long)(U_ + ip) * D + lane] * scale;
    float g = acc[(long)(U_ + in_) * D + lane] * scale;
    float ps = u * p;
    float ns = u * g;
    float u0 = user_w[(long)iu * D + lane];
    float p0 = item_w[(long)ip * D + lane];
    float n0 = item_w[(long)in_ * D + lane];
    float r = u0 * u0 + p0 * p0 + n0 * n0;
#pragma unroll
    for (int off = 32; off; off >>= 1) {
        ps += __shfl_down(ps, off, 64);
        ns += __shfl_down(ns, off, 64);
        r  += __shfl_down(r, off, 64);
    }
    if (lane == 0) {
        out[w] = ps;
        out[B_ + w] = ns;
        atomicAdd(&out[2 * B_], r);
    }
}

// ---------------- launch ----------------
extern "C" void kernel_launch(void* const* d_in, const int* in_sizes, int n_in,
                              void* d_out, int out_size, void* d_ws, size_t ws_size,
                              hipStream_t stream) {
    const int*   edge_src = (const int*)d_in[0];
    const int*   edge_dst = (const int*)d_in[1];
    const float* edge_val = (const float*)d_in[2];
    const float* user_w   = (const float*)d_in[3];
    const float* item_w   = (const float*)d_in[4];
    const int*   bu       = (const int*)d_in[5];
    const int*   bp       = (const int*)d_in[6];
    const int*   bn       = (const int*)d_in[7];

    int E_ = in_sizes[0];
    int U_ = in_sizes[3] / D;
    int I_ = in_sizes[4] / D;
    int B_ = in_sizes[5];
    int N_ = U_ + I_;
    long ND = (long)N_ * D;

    int R_ = (N_ + 511) >> 9;   // dst buckets of 512 nodes
    int SR = 8 * R_;            // slice-bucket streams (<= 8192 for N <= 512K)

    // ---- workspace layout ----
    char* p = (char*)d_ws;
    int2* col_val = (int2*)p;        p += (size_t)E_ * sizeof(int2);
    int*  deg     = (int*)p;         p += (size_t)N_ * sizeof(int);
    int*  row_ptr = (int*)p;         p += (size_t)(N_ + 1) * sizeof(int);
    int*  cur_pos = (int*)p;         p += (size_t)N_ * sizeof(int);
    int*  partial = (int*)p;         p += 1024 * sizeof(int);
    int*  sb_cnt  = (int*)p;         p += (size_t)SR * sizeof(int);
    int*  sb_base = (int*)p;         p += (size_t)SR * sizeof(int);
    int*  sb_pos  = (int*)p;         p += (size_t)SR * sizeof(int);
    p = (char*)(((uintptr_t)p + 255) & ~(uintptr_t)255);
    // overlay region: staged COO (build phase) then embeddings (compute phase)
    int*   st_src = (int*)p;
    int*   st_dst = st_src + E_;
    float* st_val = (float*)(st_dst + E_);
    float* acc = (float*)p;
    unsigned short* curb = (unsigned short*)(acc + ND);
    unsigned short* nxtb = curb + ND;
    float* out = (float*)d_out;

    int n4 = (int)(ND / 4);
    int nu4 = U_ * D / 4;
    int G = (N_ + 1023) / 1024;

    // ---- CSR build ----
    hipMemsetAsync(deg, 0, (size_t)N_ * sizeof(int), stream);
    hipMemsetAsync(sb_cnt, 0, (size_t)SR * sizeof(int), stream);
    hist_kernel<<<(E_ + 255) / 256, 256, 0, stream>>>(edge_dst, deg, sb_cnt, R_, E_);
    partial_kernel<<<G, 1024, 0, stream>>>(deg, partial, N_);
    scan_partials_kernel<<<1, 1024, 0, stream>>>(partial, G);
    scan_write_kernel<<<G, 1024, 0, stream>>>(deg, partial, row_ptr, cur_pos, N_, E_);
    scan_sb_kernel<<<1, 1024, 0, stream>>>(sb_cnt, sb_base, sb_pos, SR);
    bucket_kernel<<<(E_ + 255) / 256, 256, 0, stream>>>(
        edge_src, edge_dst, edge_val, sb_pos, st_src, st_dst, st_val, R_, E_);
    place_kernel<<<R_, 512, 0, stream>>>(
        st_src, st_dst, st_val, sb_base, sb_cnt, cur_pos, col_val, R_);

    // ---- embeddings init (overwrites staged region; stream-ordered) ----
    init_kernel<<<(n4 + 255) / 256, 256, 0, stream>>>(
        (const float4*)user_w, (const float4*)item_w,
        (float4*)acc, (ushort4*)curb, nu4, n4);

    // ---- propagation ----
    unsigned short* cb = curb;
    unsigned short* nb = nxtb;
    for (int l = 0; l < 3; ++l) {
        spmm_csr_kernel<<<(N_ + 3) / 4, 256, 0, stream>>>(
            row_ptr, col_val, (const uint4*)cb, (uint4*)nb, (float4*)acc,
            N_, (l < 2) ? 1 : 0);
        unsigned short* t = cb; cb = nb; nb = t;
    }

    // ---- epilogue ----
    hipMemsetAsync(out + 2 * B_, 0, sizeof(float), stream);
    final_kernel<<<(B_ * 64 + 255) / 256, 256, 0, stream>>>(
        acc, user_w, item_w, bu, bp, bn, out, U_, B_);
}

// Round 5
// 911.029 us; speedup vs baseline: 1.7494x; 1.7494x over previous
//
#include <hip/hip_runtime.h>

#define D 64
#define EPT 16  // edges per thread in partition

// ---- bf16 helpers ----
static __device__ __forceinline__ unsigned short f2bf(float f) {
    unsigned int u = __float_as_uint(f);
    unsigned int r = (u + 0x7FFFu + ((u >> 16) & 1u)) >> 16;
    return (unsigned short)r;
}
static __device__ __forceinline__ float bflo(unsigned int u) {
    return __uint_as_float(u << 16);
}
static __device__ __forceinline__ float bfhi(unsigned int u) {
    return __uint_as_float(u & 0xFFFF0000u);
}

// ---------------- init: fp32 acc + bf16 cur ----------------
__global__ void init_kernel(const float4* __restrict__ user_w,
                            const float4* __restrict__ item_w,
                            float4* __restrict__ acc,
                            ushort4* __restrict__ curb,
                            int n_user4, int n_tot4) {
    int i = blockIdx.x * blockDim.x + threadIdx.x;
    if (i >= n_tot4) return;
    float4 v = (i < n_user4) ? user_w[i] : item_w[i - n_user4];
    acc[i] = v;
    ushort4 b;
    b.x = f2bf(v.x); b.y = f2bf(v.y); b.z = f2bf(v.z); b.w = f2bf(v.w);
    curb[i] = b;
}

// ---------------- CSR build ----------------
// deg histogram only (150K counters: contention fine — measured R1-R3).
__global__ void hist_kernel(const int* __restrict__ dst, int* __restrict__ deg, int E_) {
    int i = blockIdx.x * blockDim.x + threadIdx.x;
    if (i < E_) atomicAdd(&deg[dst[i]], 1);
}

__global__ void partial_kernel(const int* __restrict__ deg, int* __restrict__ partial, int N_) {
    __shared__ int sh[1024];
    int tid = threadIdx.x;
    int i = blockIdx.x * 1024 + tid;
    sh[tid] = (i < N_) ? deg[i] : 0;
    __syncthreads();
    for (int off = 512; off; off >>= 1) {
        if (tid < off) sh[tid] += sh[tid + off];
        __syncthreads();
    }
    if (tid == 0) partial[blockIdx.x] = sh[0];
}

__global__ void scan_partials_kernel(int* __restrict__ partial, int G_) {
    __shared__ int sh[1024];
    int tid = threadIdx.x;
    int v = (tid < G_) ? partial[tid] : 0;
    sh[tid] = v;
    __syncthreads();
    for (int off = 1; off < 1024; off <<= 1) {
        int t = (tid >= off) ? sh[tid - off] : 0;
        __syncthreads();
        sh[tid] += t;
        __syncthreads();
    }
    if (tid < G_) partial[tid] = sh[tid] - v;  // exclusive
}

// block-local scan + offset -> row_ptr, cur_pos, and per-bucket bases g_pos.
__global__ void scan_write_kernel(const int* __restrict__ deg,
                                  const int* __restrict__ partial,
                                  int* __restrict__ row_ptr,
                                  int* __restrict__ cur_pos,
                                  int* __restrict__ g_pos,
                                  int N_, int E_) {
    __shared__ int sh[1024];
    int tid = threadIdx.x;
    int i = blockIdx.x * 1024 + tid;
    int v = (i < N_) ? deg[i] : 0;
    sh[tid] = v;
    __syncthreads();
    for (int off = 1; off < 1024; off <<= 1) {
        int t = (tid >= off) ? sh[tid - off] : 0;
        __syncthreads();
        sh[tid] += t;
        __syncthreads();
    }
    if (i < N_) {
        int excl = sh[tid] - v + partial[blockIdx.x];
        row_ptr[i] = excl;
        cur_pos[i] = excl;
        if ((i & 511) == 0) g_pos[i >> 9] = excl;  // bucket append cursor
    }
    if (i == N_ - 1) row_ptr[N_] = E_;
}

// partition: LDS histogram + LDS ranks; ONE global atomic per (block,bucket).
// st entry: {src, (val_bf16<<16) | dst_off}. Runs are bucket-contiguous per block.
__global__ void partition_kernel(const int* __restrict__ src,
                                 const int* __restrict__ dst,
                                 const float* __restrict__ val,
                                 int* __restrict__ g_pos,
                                 int2* __restrict__ st,
                                 int K_, int E_) {
    __shared__ int cnt[512];
    __shared__ int base[512];
    for (int k = threadIdx.x; k < K_; k += 256) cnt[k] = 0;
    __syncthreads();
    int b0 = blockIdx.x * (256 * EPT);
    int myk[EPT], myr[EPT], mysrc[EPT];
    unsigned mypk[EPT];
#pragma unroll
    for (int e = 0; e < EPT; ++e) {
        int i = b0 + e * 256 + threadIdx.x;
        if (i < E_) {
            int d = dst[i];
            int k = d >> 9;
            myk[e] = k;
            mysrc[e] = src[i];
            mypk[e] = ((unsigned)f2bf(val[i]) << 16) | (unsigned)(d & 511);
            myr[e] = atomicAdd(&cnt[k], 1);
        } else {
            myk[e] = -1;
        }
    }
    __syncthreads();
    for (int k = threadIdx.x; k < K_; k += 256) {
        int c = cnt[k];
        base[k] = c ? atomicAdd(&g_pos[k], c) : 0;
    }
    __syncthreads();
#pragma unroll
    for (int e = 0; e < EPT; ++e) {
        if (myk[e] >= 0)
            st[base[myk[e]] + myr[e]] = make_int2(mysrc[e], (int)mypk[e]);
    }
}

// place: one block per bucket; sequential read of staged span, scatter into
// this bucket's ~130KB col_val window (L2-resident -> lines fill, amp~1x).
__global__ void place_kernel(const int2* __restrict__ st,
                             const int* __restrict__ row_ptr,
                             int* __restrict__ cur_pos,
                             int2* __restrict__ col_val, int N_) {
    int rbeg = blockIdx.x << 9;
    int rend = min(rbeg + 512, N_);
    int beg = row_ptr[rbeg];
    int end = row_ptr[rend];
    for (int e = beg + threadIdx.x; e < end; e += blockDim.x) {
        int2 cv = st[e];
        int d = rbeg + ((unsigned)cv.y & 511u);
        int p = atomicAdd(&cur_pos[d], 1);
        col_val[p] = cv;
    }
}

// ---------------- CSR gather SpMM, bf16 rows, 16B/lane loads ----------------
__global__ void spmm_csr_kernel(const int* __restrict__ row_ptr,
                                const int2* __restrict__ col_val,
                                const uint4* __restrict__ xb,
                                uint4* __restrict__ nxtb,
                                float4* __restrict__ acc,
                                int N_, int write_nxt) {
    int row = (int)((blockIdx.x * blockDim.x + threadIdx.x) >> 6);
    int lane = threadIdx.x & 63;
    if (row >= N_) return;
    int q = lane >> 3;    // which of 8 edges in the group
    int lid = lane & 7;   // which 16B chunk of the row
    int beg = row_ptr[row];
    int end = row_ptr[row + 1];
    float s0 = 0, s1 = 0, s2 = 0, s3 = 0, s4 = 0, s5 = 0, s6 = 0, s7 = 0;
    for (int base = beg; base < end; base += 64) {
        int e = base + lane;
        int c = 0;
        float v = 0.f;
        if (e < end) {
            int2 cv = col_val[e];
            c = cv.x;
            v = bfhi((unsigned)cv.y);   // val in high 16 bits
        }
        int m = min(64, end - base);
        int m8 = (m + 7) & ~7;
        for (int j = 0; j < m8; j += 8) {
            int cj = __shfl(c, j + q, 64);
            float vj = __shfl(v, j + q, 64);
            uint4 t = xb[(long)cj * 8 + lid];
            s0 += vj * bflo(t.x); s1 += vj * bfhi(t.x);
            s2 += vj * bflo(t.y); s3 += vj * bfhi(t.y);
            s4 += vj * bflo(t.z); s5 += vj * bfhi(t.z);
            s6 += vj * bflo(t.w); s7 += vj * bfhi(t.w);
        }
    }
#pragma unroll
    for (int off = 32; off >= 8; off >>= 1) {
        s0 += __shfl_xor(s0, off, 64);
        s1 += __shfl_xor(s1, off, 64);
        s2 += __shfl_xor(s2, off, 64);
        s3 += __shfl_xor(s3, off, 64);
        s4 += __shfl_xor(s4, off, 64);
        s5 += __shfl_xor(s5, off, 64);
        s6 += __shfl_xor(s6, off, 64);
        s7 += __shfl_xor(s7, off, 64);
    }
    if (q == 0) {
        if (write_nxt) {
            uint4 b;
            b.x = (unsigned)f2bf(s0) | ((unsigned)f2bf(s1) << 16);
            b.y = (unsigned)f2bf(s2) | ((unsigned)f2bf(s3) << 16);
            b.z = (unsigned)f2bf(s4) | ((unsigned)f2bf(s5) << 16);
            b.w = (unsigned)f2bf(s6) | ((unsigned)f2bf(s7) << 16);
            nxtb[(long)row * 8 + lid] = b;
        }
        float4* ap = acc + (long)row * 16 + lid * 2;
        float4 a0 = ap[0];
        a0.x += s0; a0.y += s1; a0.z += s2; a0.w += s3;
        ap[0] = a0;
        float4 a1 = ap[1];
        a1.x += s4; a1.y += s5; a1.z += s6; a1.w += s7;
        ap[1] = a1;
    }
}

// ---------------- epilogue ----------------
__global__ void final_kernel(const float* __restrict__ acc,
                             const float* __restrict__ user_w,
                             const float* __restrict__ item_w,
                             const int* __restrict__ bu,
                             const int* __restrict__ bp,
                             const int* __restrict__ bn,
                             float* __restrict__ out,
                             int U_, int B_) {
    int w = (int)((blockIdx.x * blockDim.x + threadIdx.x) >> 6);
    int lane = threadIdx.x & 63;
    if (w >= B_) return;
    int iu = bu[w], ip = bp[w], in_ = bn[w];
    const float scale = 0.25f;  // 1/(L+1)
    float u = acc[(long)iu * D + lane] * scale;
    float p = acc[(long)(U_ + ip) * D + lane] * scale;
    float g = acc[(long)(U_ + in_) * D + lane] * scale;
    float ps = u * p;
    float ns = u * g;
    float u0 = user_w[(long)iu * D + lane];
    float p0 = item_w[(long)ip * D + lane];
    float n0 = item_w[(long)in_ * D + lane];
    float r = u0 * u0 + p0 * p0 + n0 * n0;
#pragma unroll
    for (int off = 32; off; off >>= 1) {
        ps += __shfl_down(ps, off, 64);
        ns += __shfl_down(ns, off, 64);
        r  += __shfl_down(r, off, 64);
    }
    if (lane == 0) {
        out[w] = ps;
        out[B_ + w] = ns;
        atomicAdd(&out[2 * B_], r);
    }
}

// ---------------- launch ----------------
extern "C" void kernel_launch(void* const* d_in, const int* in_sizes, int n_in,
                              void* d_out, int out_size, void* d_ws, size_t ws_size,
                              hipStream_t stream) {
    const int*   edge_src = (const int*)d_in[0];
    const int*   edge_dst = (const int*)d_in[1];
    const float* edge_val = (const float*)d_in[2];
    const float* user_w   = (const float*)d_in[3];
    const float* item_w   = (const float*)d_in[4];
    const int*   bu       = (const int*)d_in[5];
    const int*   bp       = (const int*)d_in[6];
    const int*   bn       = (const int*)d_in[7];

    int E_ = in_sizes[0];
    int U_ = in_sizes[3] / D;
    int I_ = in_sizes[4] / D;
    int B_ = in_sizes[5];
    int N_ = U_ + I_;
    long ND = (long)N_ * D;
    int K_ = (N_ + 511) >> 9;   // dst buckets of 512 nodes (K_ <= 512 assumed)

    // ---- workspace layout ----
    char* p = (char*)d_ws;
    int2* col_val = (int2*)p;        p += (size_t)E_ * sizeof(int2);
    int*  deg     = (int*)p;         p += (size_t)N_ * sizeof(int);
    int*  row_ptr = (int*)p;         p += (size_t)(N_ + 1) * sizeof(int);
    int*  cur_pos = (int*)p;         p += (size_t)N_ * sizeof(int);
    int*  partial = (int*)p;         p += 1024 * sizeof(int);
    int*  g_pos   = (int*)p;         p += 512 * sizeof(int);
    p = (char*)(((uintptr_t)p + 255) & ~(uintptr_t)255);
    // overlay: staged edges (build phase) then embeddings (compute phase)
    int2* st = (int2*)p;
    float* acc = (float*)p;
    unsigned short* curb = (unsigned short*)(acc + ND);
    unsigned short* nxtb = curb + ND;
    float* out = (float*)d_out;

    int n4 = (int)(ND / 4);
    int nu4 = U_ * D / 4;
    int G = (N_ + 1023) / 1024;

    // ---- CSR build ----
    hipMemsetAsync(deg, 0, (size_t)N_ * sizeof(int), stream);
    hist_kernel<<<(E_ + 255) / 256, 256, 0, stream>>>(edge_dst, deg, E_);
    partial_kernel<<<G, 1024, 0, stream>>>(deg, partial, N_);
    scan_partials_kernel<<<1, 1024, 0, stream>>>(partial, G);
    scan_write_kernel<<<G, 1024, 0, stream>>>(deg, partial, row_ptr, cur_pos,
                                              g_pos, N_, E_);
    partition_kernel<<<(E_ + 256 * EPT - 1) / (256 * EPT), 256, 0, stream>>>(
        edge_src, edge_dst, edge_val, g_pos, st, K_, E_);
    place_kernel<<<K_, 1024, 0, stream>>>(st, row_ptr, cur_pos, col_val, N_);

    // ---- embeddings init (overwrites staged region; stream-ordered) ----
    init_kernel<<<(n4 + 255) / 256, 256, 0, stream>>>(
        (const float4*)user_w, (const float4*)item_w,
        (float4*)acc, (ushort4*)curb, nu4, n4);

    // ---- propagation ----
    unsigned short* cb = curb;
    unsigned short* nb = nxtb;
    for (int l = 0; l < 3; ++l) {
        spmm_csr_kernel<<<(N_ + 3) / 4, 256, 0, stream>>>(
            row_ptr, col_val, (const uint4*)cb, (uint4*)nb, (float4*)acc,
            N_, (l < 2) ? 1 : 0);
        unsigned short* t = cb; cb = nb; nb = t;
    }

    // ---- epilogue ----
    hipMemsetAsync(out + 2 * B_, 0, sizeof(float), stream);
    final_kernel<<<(B_ * 64 + 255) / 256, 256, 0, stream>>>(
        acc, user_w, item_w, bu, bp, bn, out, U_, B_);
}

// Round 6
// 682.823 us; speedup vs baseline: 2.3341x; 1.3342x over previous
//
#include <hip/hip_runtime.h>

#define D 64
#define EPT 16    // edges per thread in partition
#define EPTC 32   // edges per thread in count

// ---- bf16 helpers ----
static __device__ __forceinline__ unsigned short f2bf(float f) {
    unsigned int u = __float_as_uint(f);
    unsigned int r = (u + 0x7FFFu + ((u >> 16) & 1u)) >> 16;
    return (unsigned short)r;
}
static __device__ __forceinline__ float bflo(unsigned int u) {
    return __uint_as_float(u << 16);
}
static __device__ __forceinline__ float bfhi(unsigned int u) {
    return __uint_as_float(u & 0xFFFF0000u);
}

// ---------------- init: fp32 acc + bf16 cur ----------------
__global__ void init_kernel(const float4* __restrict__ user_w,
                            const float4* __restrict__ item_w,
                            float4* __restrict__ acc,
                            ushort4* __restrict__ curb,
                            int n_user4, int n_tot4) {
    int i = blockIdx.x * blockDim.x + threadIdx.x;
    if (i >= n_tot4) return;
    float4 v = (i < n_user4) ? user_w[i] : item_w[i - n_user4];
    acc[i] = v;
    ushort4 b;
    b.x = f2bf(v.x); b.y = f2bf(v.y); b.z = f2bf(v.z); b.w = f2bf(v.w);
    curb[i] = b;
}

// ---------------- bucket counts (replaces per-node hist) ----------------
// LDS histogram over K buckets; ONE global atomic per (block,bucket).
__global__ void count_kernel(const int* __restrict__ dst,
                             int* __restrict__ bkt_cnt, int K_, int E_) {
    __shared__ int cnt[512];
    for (int k = threadIdx.x; k < K_; k += 256) cnt[k] = 0;
    __syncthreads();
    int b0 = blockIdx.x * (256 * EPTC);
#pragma unroll 4
    for (int e = 0; e < EPTC; ++e) {
        int i = b0 + e * 256 + threadIdx.x;
        if (i < E_) atomicAdd(&cnt[dst[i] >> 9], 1);
    }
    __syncthreads();
    for (int k = threadIdx.x; k < K_; k += 256) {
        int c = cnt[k];
        if (c) atomicAdd(&bkt_cnt[k], c);
    }
}

// single block (512 threads): exclusive scan of K (<=512) bucket counts.
__global__ void scan_bkt_kernel(const int* __restrict__ cnt,
                                int* __restrict__ base,
                                int* __restrict__ gpos, int K_, int E_) {
    __shared__ int sh[512];
    int tid = threadIdx.x;
    int v = (tid < K_) ? cnt[tid] : 0;
    sh[tid] = v;
    __syncthreads();
    for (int off = 1; off < 512; off <<= 1) {
        int t = (tid >= off) ? sh[tid - off] : 0;
        __syncthreads();
        sh[tid] += t;
        __syncthreads();
    }
    if (tid < K_) {
        int e = sh[tid] - v;
        base[tid] = e;
        gpos[tid] = e;
    }
    if (tid == 0) base[K_] = E_;
}

// partition: LDS histogram + LDS ranks; ONE global atomic per (block,bucket).
// st entry: {src, (val_bf16<<16) | dst_off9}. Runs are bucket-contiguous.
__global__ void partition_kernel(const int* __restrict__ src,
                                 const int* __restrict__ dst,
                                 const float* __restrict__ val,
                                 int* __restrict__ g_pos,
                                 int2* __restrict__ st,
                                 int K_, int E_) {
    __shared__ int cnt[512];
    __shared__ int base[512];
    for (int k = threadIdx.x; k < K_; k += 256) cnt[k] = 0;
    __syncthreads();
    int b0 = blockIdx.x * (256 * EPT);
    int myk[EPT], myr[EPT], mysrc[EPT];
    unsigned mypk[EPT];
#pragma unroll
    for (int e = 0; e < EPT; ++e) {
        int i = b0 + e * 256 + threadIdx.x;
        if (i < E_) {
            int d = dst[i];
            int k = d >> 9;
            myk[e] = k;
            mysrc[e] = src[i];
            mypk[e] = ((unsigned)f2bf(val[i]) << 16) | (unsigned)(d & 511);
            myr[e] = atomicAdd(&cnt[k], 1);
        } else {
            myk[e] = -1;
        }
    }
    __syncthreads();
    for (int k = threadIdx.x; k < K_; k += 256) {
        int c = cnt[k];
        base[k] = c ? atomicAdd(&g_pos[k], c) : 0;
    }
    __syncthreads();
#pragma unroll
    for (int e = 0; e < EPT; ++e) {
        if (myk[e] >= 0)
            st[base[myk[e]] + myr[e]] = make_int2(mysrc[e], (int)mypk[e]);
    }
}

// place: one block per bucket. Derives local degrees + row_ptr in LDS, then
// scatters the staged span into this bucket's ~130KB col_val window
// (L2-resident -> lines fill before eviction). All per-edge atomics are LDS.
__global__ void place_kernel(const int2* __restrict__ st,
                             const int* __restrict__ bkt_base,
                             int* __restrict__ row_ptr,
                             int2* __restrict__ col_val,
                             int K_, int N_, int E_) {
    __shared__ int ldeg[512];
    __shared__ int sh[512];
    __shared__ int lcur[512];
    int b = blockIdx.x;
    int tid = threadIdx.x;
    int rbeg = b << 9;
    int beg = bkt_base[b];
    int end = bkt_base[b + 1];
    if (tid < 512) ldeg[tid] = 0;
    __syncthreads();
    for (int e = beg + tid; e < end; e += 1024)
        atomicAdd(&ldeg[(unsigned)st[e].y & 511u], 1);
    __syncthreads();
    int v = 0;
    if (tid < 512) {
        v = ldeg[tid];
        sh[tid] = v;
    }
    __syncthreads();
    for (int off = 1; off < 512; off <<= 1) {
        int t = 0;
        if (tid < 512 && tid >= off) t = sh[tid - off];
        __syncthreads();
        if (tid < 512) sh[tid] += t;
        __syncthreads();
    }
    if (tid < 512) {
        int excl = sh[tid] - v;
        lcur[tid] = excl;
        int gi = rbeg + tid;
        if (gi < N_) row_ptr[gi] = beg + excl;
    }
    if (b == K_ - 1 && tid == 0) row_ptr[N_] = E_;
    __syncthreads();
    for (int e = beg + tid; e < end; e += 1024) {
        int2 cv = st[e];
        int p = beg + atomicAdd(&lcur[(unsigned)cv.y & 511u], 1);
        col_val[p] = cv;
    }
}

// ---------------- CSR gather SpMM, bf16 rows, 16B/lane loads ----------------
__global__ void spmm_csr_kernel(const int* __restrict__ row_ptr,
                                const int2* __restrict__ col_val,
                                const uint4* __restrict__ xb,
                                uint4* __restrict__ nxtb,
                                float4* __restrict__ acc,
                                int N_, int write_nxt) {
    int row = (int)((blockIdx.x * blockDim.x + threadIdx.x) >> 6);
    int lane = threadIdx.x & 63;
    if (row >= N_) return;
    int q = lane >> 3;    // which of 8 edges in the group
    int lid = lane & 7;   // which 16B chunk of the row
    int beg = row_ptr[row];
    int end = row_ptr[row + 1];
    float s0 = 0, s1 = 0, s2 = 0, s3 = 0, s4 = 0, s5 = 0, s6 = 0, s7 = 0;
    for (int base = beg; base < end; base += 64) {
        int e = base + lane;
        int c = 0;
        float v = 0.f;
        if (e < end) {
            int2 cv = col_val[e];
            c = cv.x;
            v = bfhi((unsigned)cv.y);   // val in high 16 bits
        }
        int m = min(64, end - base);
        int m8 = (m + 7) & ~7;
        for (int j = 0; j < m8; j += 8) {
            int cj = __shfl(c, j + q, 64);
            float vj = __shfl(v, j + q, 64);
            uint4 t = xb[(long)cj * 8 + lid];
            s0 += vj * bflo(t.x); s1 += vj * bfhi(t.x);
            s2 += vj * bflo(t.y); s3 += vj * bfhi(t.y);
            s4 += vj * bflo(t.z); s5 += vj * bfhi(t.z);
            s6 += vj * bflo(t.w); s7 += vj * bfhi(t.w);
        }
    }
#pragma unroll
    for (int off = 32; off >= 8; off >>= 1) {
        s0 += __shfl_xor(s0, off, 64);
        s1 += __shfl_xor(s1, off, 64);
        s2 += __shfl_xor(s2, off, 64);
        s3 += __shfl_xor(s3, off, 64);
        s4 += __shfl_xor(s4, off, 64);
        s5 += __shfl_xor(s5, off, 64);
        s6 += __shfl_xor(s6, off, 64);
        s7 += __shfl_xor(s7, off, 64);
    }
    if (q == 0) {
        if (write_nxt) {
            uint4 b;
            b.x = (unsigned)f2bf(s0) | ((unsigned)f2bf(s1) << 16);
            b.y = (unsigned)f2bf(s2) | ((unsigned)f2bf(s3) << 16);
            b.z = (unsigned)f2bf(s4) | ((unsigned)f2bf(s5) << 16);
            b.w = (unsigned)f2bf(s6) | ((unsigned)f2bf(s7) << 16);
            nxtb[(long)row * 8 + lid] = b;
        }
        float4* ap = acc + (long)row * 16 + lid * 2;
        float4 a0 = ap[0];
        a0.x += s0; a0.y += s1; a0.z += s2; a0.w += s3;
        ap[0] = a0;
        float4 a1 = ap[1];
        a1.x += s4; a1.y += s5; a1.z += s6; a1.w += s7;
        ap[1] = a1;
    }
}

// ---------------- epilogue ----------------
__global__ void final_kernel(const float* __restrict__ acc,
                             const float* __restrict__ user_w,
                             const float* __restrict__ item_w,
                             const int* __restrict__ bu,
                             const int* __restrict__ bp,
                             const int* __restrict__ bn,
                             float* __restrict__ out,
                             int U_, int B_) {
    int w = (int)((blockIdx.x * blockDim.x + threadIdx.x) >> 6);
    int lane = threadIdx.x & 63;
    if (w >= B_) return;
    int iu = bu[w], ip = bp[w], in_ = bn[w];
    const float scale = 0.25f;  // 1/(L+1)
    float u = acc[(long)iu * D + lane] * scale;
    float p = acc[(long)(U_ + ip) * D + lane] * scale;
    float g = acc[(long)(U_ + in_) * D + lane] * scale;
    float ps = u * p;
    float ns = u * g;
    float u0 = user_w[(long)iu * D + lane];
    float p0 = item_w[(long)ip * D + lane];
    float n0 = item_w[(long)in_ * D + lane];
    float r = u0 * u0 + p0 * p0 + n0 * n0;
#pragma unroll
    for (int off = 32; off; off >>= 1) {
        ps += __shfl_down(ps, off, 64);
        ns += __shfl_down(ns, off, 64);
        r  += __shfl_down(r, off, 64);
    }
    if (lane == 0) {
        out[w] = ps;
        out[B_ + w] = ns;
        atomicAdd(&out[2 * B_], r);
    }
}

// ---------------- launch ----------------
extern "C" void kernel_launch(void* const* d_in, const int* in_sizes, int n_in,
                              void* d_out, int out_size, void* d_ws, size_t ws_size,
                              hipStream_t stream) {
    const int*   edge_src = (const int*)d_in[0];
    const int*   edge_dst = (const int*)d_in[1];
    const float* edge_val = (const float*)d_in[2];
    const float* user_w   = (const float*)d_in[3];
    const float* item_w   = (const float*)d_in[4];
    const int*   bu       = (const int*)d_in[5];
    const int*   bp       = (const int*)d_in[6];
    const int*   bn       = (const int*)d_in[7];

    int E_ = in_sizes[0];
    int U_ = in_sizes[3] / D;
    int I_ = in_sizes[4] / D;
    int B_ = in_sizes[5];
    int N_ = U_ + I_;
    long ND = (long)N_ * D;
    int K_ = (N_ + 511) >> 9;   // dst buckets of 512 nodes (K_ <= 512 assumed)

    // ---- workspace layout ----
    char* p = (char*)d_ws;
    int2* col_val  = (int2*)p;       p += (size_t)E_ * sizeof(int2);
    int*  row_ptr  = (int*)p;        p += (size_t)(N_ + 1) * sizeof(int);
    int*  bkt_cnt  = (int*)p;        p += 512 * sizeof(int);
    int*  bkt_base = (int*)p;        p += 513 * sizeof(int);
    int*  g_pos    = (int*)p;        p += 512 * sizeof(int);
    p = (char*)(((uintptr_t)p + 255) & ~(uintptr_t)255);
    // overlay: staged edges (build phase) then embeddings (compute phase)
    int2* st = (int2*)p;
    float* acc = (float*)p;
    unsigned short* curb = (unsigned short*)(acc + ND);
    unsigned short* nxtb = curb + ND;
    float* out = (float*)d_out;

    int n4 = (int)(ND / 4);
    int nu4 = U_ * D / 4;

    // ---- CSR build ----
    hipMemsetAsync(bkt_cnt, 0, 512 * sizeof(int), stream);
    count_kernel<<<(E_ + 256 * EPTC - 1) / (256 * EPTC), 256, 0, stream>>>(
        edge_dst, bkt_cnt, K_, E_);
    scan_bkt_kernel<<<1, 512, 0, stream>>>(bkt_cnt, bkt_base, g_pos, K_, E_);
    partition_kernel<<<(E_ + 256 * EPT - 1) / (256 * EPT), 256, 0, stream>>>(
        edge_src, edge_dst, edge_val, g_pos, st, K_, E_);
    place_kernel<<<K_, 1024, 0, stream>>>(st, bkt_base, row_ptr, col_val,
                                          K_, N_, E_);

    // ---- embeddings init (overwrites staged region; stream-ordered) ----
    init_kernel<<<(n4 + 255) / 256, 256, 0, stream>>>(
        (const float4*)user_w, (const float4*)item_w,
        (float4*)acc, (ushort4*)curb, nu4, n4);

    // ---- propagation ----
    unsigned short* cb = curb;
    unsigned short* nb = nxtb;
    for (int l = 0; l < 3; ++l) {
        spmm_csr_kernel<<<(N_ + 3) / 4, 256, 0, stream>>>(
            row_ptr, col_val, (const uint4*)cb, (uint4*)nb, (float4*)acc,
            N_, (l < 2) ? 1 : 0);
        unsigned short* t = cb; cb = nb; nb = t;
    }

    // ---- epilogue ----
    hipMemsetAsync(out + 2 * B_, 0, sizeof(float), stream);
    final_kernel<<<(B_ * 64 + 255) / 256, 256, 0, stream>>>(
        acc, user_w, item_w, bu, bp, bn, out, U_, B_);
}

// Round 7
// 584.842 us; speedup vs baseline: 2.7251x; 1.1675x over previous
//
#include <hip/hip_runtime.h>

#define D 64
#define EPT 16    // edges per thread in partition
#define EPTC 32   // edges per thread in count

// ---- bf16 helpers ----
static __device__ __forceinline__ unsigned short f2bf(float f) {
    unsigned int u = __float_as_uint(f);
    unsigned int r = (u + 0x7FFFu + ((u >> 16) & 1u)) >> 16;
    return (unsigned short)r;
}
static __device__ __forceinline__ float bflo(unsigned int u) {
    return __uint_as_float(u << 16);
}
static __device__ __forceinline__ float bfhi(unsigned int u) {
    return __uint_as_float(u & 0xFFFF0000u);
}

// ---------------- init: fp32 acc + bf16 cur ----------------
__global__ void init_kernel(const float4* __restrict__ user_w,
                            const float4* __restrict__ item_w,
                            float4* __restrict__ acc,
                            ushort4* __restrict__ curb,
                            int n_user4, int n_tot4) {
    int i = blockIdx.x * blockDim.x + threadIdx.x;
    if (i >= n_tot4) return;
    float4 v = (i < n_user4) ? user_w[i] : item_w[i - n_user4];
    acc[i] = v;
    ushort4 b;
    b.x = f2bf(v.x); b.y = f2bf(v.y); b.z = f2bf(v.z); b.w = f2bf(v.w);
    curb[i] = b;
}

// ---------------- bucket counts ----------------
// LDS histogram over K buckets; ONE global atomic per (block,bucket).
__global__ void count_kernel(const int* __restrict__ dst,
                             int* __restrict__ bkt_cnt, int K_, int E_) {
    __shared__ int cnt[512];
    for (int k = threadIdx.x; k < K_; k += 256) cnt[k] = 0;
    __syncthreads();
    int b0 = blockIdx.x * (256 * EPTC);
#pragma unroll 4
    for (int e = 0; e < EPTC; ++e) {
        int i = b0 + e * 256 + threadIdx.x;
        if (i < E_) atomicAdd(&cnt[dst[i] >> 9], 1);
    }
    __syncthreads();
    for (int k = threadIdx.x; k < K_; k += 256) {
        int c = cnt[k];
        if (c) atomicAdd(&bkt_cnt[k], c);
    }
}

// single block (512 threads): exclusive scan of K (<=512) bucket counts.
__global__ void scan_bkt_kernel(const int* __restrict__ cnt,
                                int* __restrict__ base,
                                int* __restrict__ gpos, int K_, int E_) {
    __shared__ int sh[512];
    int tid = threadIdx.x;
    int v = (tid < K_) ? cnt[tid] : 0;
    sh[tid] = v;
    __syncthreads();
    for (int off = 1; off < 512; off <<= 1) {
        int t = (tid >= off) ? sh[tid - off] : 0;
        __syncthreads();
        sh[tid] += t;
        __syncthreads();
    }
    if (tid < K_) {
        int e = sh[tid] - v;
        base[tid] = e;
        gpos[tid] = e;
    }
    if (tid == 0) base[K_] = E_;
}

// partition: LDS histogram + LDS ranks; ONE global atomic per (block,bucket).
// st entry: {src, (val_bf16<<16) | dst_off9}. Runs are bucket-contiguous.
__global__ void partition_kernel(const int* __restrict__ src,
                                 const int* __restrict__ dst,
                                 const float* __restrict__ val,
                                 int* __restrict__ g_pos,
                                 int2* __restrict__ st,
                                 int K_, int E_) {
    __shared__ int cnt[512];
    __shared__ int base[512];
    for (int k = threadIdx.x; k < K_; k += 256) cnt[k] = 0;
    __syncthreads();
    int b0 = blockIdx.x * (256 * EPT);
    int myk[EPT], myr[EPT], mysrc[EPT];
    unsigned mypk[EPT];
#pragma unroll
    for (int e = 0; e < EPT; ++e) {
        int i = b0 + e * 256 + threadIdx.x;
        if (i < E_) {
            int d = dst[i];
            int k = d >> 9;
            myk[e] = k;
            mysrc[e] = src[i];
            mypk[e] = ((unsigned)f2bf(val[i]) << 16) | (unsigned)(d & 511);
            myr[e] = atomicAdd(&cnt[k], 1);
        } else {
            myk[e] = -1;
        }
    }
    __syncthreads();
    for (int k = threadIdx.x; k < K_; k += 256) {
        int c = cnt[k];
        base[k] = c ? atomicAdd(&g_pos[k], c) : 0;
    }
    __syncthreads();
#pragma unroll
    for (int e = 0; e < EPT; ++e) {
        if (myk[e] >= 0)
            st[base[myk[e]] + myr[e]] = make_int2(mysrc[e], (int)mypk[e]);
    }
}

// place: one block per bucket; derives local degrees + row_ptr in LDS, then
// scatters into this bucket's L2-resident col_val window. Per-edge atomics LDS.
__global__ void place_kernel(const int2* __restrict__ st,
                             const int* __restrict__ bkt_base,
                             int* __restrict__ row_ptr,
                             int2* __restrict__ col_val,
                             int K_, int N_, int E_) {
    __shared__ int ldeg[512];
    __shared__ int sh[512];
    __shared__ int lcur[512];
    int b = blockIdx.x;
    int tid = threadIdx.x;
    int rbeg = b << 9;
    int beg = bkt_base[b];
    int end = bkt_base[b + 1];
    if (tid < 512) ldeg[tid] = 0;
    __syncthreads();
    for (int e = beg + tid; e < end; e += 1024)
        atomicAdd(&ldeg[(unsigned)st[e].y & 511u], 1);
    __syncthreads();
    int v = 0;
    if (tid < 512) {
        v = ldeg[tid];
        sh[tid] = v;
    }
    __syncthreads();
    for (int off = 1; off < 512; off <<= 1) {
        int t = 0;
        if (tid < 512 && tid >= off) t = sh[tid - off];
        __syncthreads();
        if (tid < 512) sh[tid] += t;
        __syncthreads();
    }
    if (tid < 512) {
        int excl = sh[tid] - v;
        lcur[tid] = excl;
        int gi = rbeg + tid;
        if (gi < N_) row_ptr[gi] = beg + excl;
    }
    if (b == K_ - 1 && tid == 0) row_ptr[N_] = E_;
    __syncthreads();
    for (int e = beg + tid; e < end; e += 1024) {
        int2 cv = st[e];
        int p = beg + atomicAdd(&lcur[(unsigned)cv.y & 511u], 1);
        col_val[p] = cv;
    }
}

// ---------------- CSR gather SpMM, bf16 rows, 16B/lane loads ----------------
__global__ void spmm_csr_kernel(const int* __restrict__ row_ptr,
                                const int2* __restrict__ col_val,
                                const uint4* __restrict__ xb,
                                uint4* __restrict__ nxtb,
                                float4* __restrict__ acc,
                                int N_, int write_nxt) {
    int row = (int)((blockIdx.x * blockDim.x + threadIdx.x) >> 6);
    int lane = threadIdx.x & 63;
    if (row >= N_) return;
    int q = lane >> 3;    // which of 8 edges in the group
    int lid = lane & 7;   // which 16B chunk of the row
    int beg = row_ptr[row];
    int end = row_ptr[row + 1];
    float s0 = 0, s1 = 0, s2 = 0, s3 = 0, s4 = 0, s5 = 0, s6 = 0, s7 = 0;
    for (int base = beg; base < end; base += 64) {
        int e = base + lane;
        int c = 0;
        float v = 0.f;
        if (e < end) {
            int2 cv = col_val[e];
            c = cv.x;
            v = bfhi((unsigned)cv.y);   // val in high 16 bits
        }
        int m = min(64, end - base);
        int m8 = (m + 7) & ~7;
        for (int j = 0; j < m8; j += 8) {
            int cj = __shfl(c, j + q, 64);
            float vj = __shfl(v, j + q, 64);
            uint4 t = xb[(long)cj * 8 + lid];
            s0 += vj * bflo(t.x); s1 += vj * bfhi(t.x);
            s2 += vj * bflo(t.y); s3 += vj * bfhi(t.y);
            s4 += vj * bflo(t.z); s5 += vj * bfhi(t.z);
            s6 += vj * bflo(t.w); s7 += vj * bfhi(t.w);
        }
    }
#pragma unroll
    for (int off = 32; off >= 8; off >>= 1) {
        s0 += __shfl_xor(s0, off, 64);
        s1 += __shfl_xor(s1, off, 64);
        s2 += __shfl_xor(s2, off, 64);
        s3 += __shfl_xor(s3, off, 64);
        s4 += __shfl_xor(s4, off, 64);
        s5 += __shfl_xor(s5, off, 64);
        s6 += __shfl_xor(s6, off, 64);
        s7 += __shfl_xor(s7, off, 64);
    }
    if (q == 0) {
        if (write_nxt) {
            uint4 b;
            b.x = (unsigned)f2bf(s0) | ((unsigned)f2bf(s1) << 16);
            b.y = (unsigned)f2bf(s2) | ((unsigned)f2bf(s3) << 16);
            b.z = (unsigned)f2bf(s4) | ((unsigned)f2bf(s5) << 16);
            b.w = (unsigned)f2bf(s6) | ((unsigned)f2bf(s7) << 16);
            nxtb[(long)row * 8 + lid] = b;
        }
        float4* ap = acc + (long)row * 16 + lid * 2;
        float4 a0 = ap[0];
        a0.x += s0; a0.y += s1; a0.z += s2; a0.w += s3;
        ap[0] = a0;
        float4 a1 = ap[1];
        a1.x += s4; a1.y += s5; a1.z += s6; a1.w += s7;
        ap[1] = a1;
    }
}

// ---------------- epilogue ----------------
// reg_loss: wave shuffle -> block LDS -> ONE partial per block (no global
// atomic contention — R6's 107us was 8192 same-address atomic RMWs).
__global__ void final_kernel(const float* __restrict__ acc,
                             const float* __restrict__ user_w,
                             const float* __restrict__ item_w,
                             const int* __restrict__ bu,
                             const int* __restrict__ bp,
                             const int* __restrict__ bn,
                             float* __restrict__ out,
                             float* __restrict__ red,
                             int U_, int B_) {
    __shared__ float pr[4];
    int w = (int)((blockIdx.x * blockDim.x + threadIdx.x) >> 6);
    int lane = threadIdx.x & 63;
    bool valid = (w < B_);
    float ps = 0.f, ns = 0.f, r = 0.f;
    if (valid) {
        int iu = bu[w], ip = bp[w], in_ = bn[w];
        const float scale = 0.25f;  // 1/(L+1)
        float u = acc[(long)iu * D + lane] * scale;
        float p = acc[(long)(U_ + ip) * D + lane] * scale;
        float g = acc[(long)(U_ + in_) * D + lane] * scale;
        ps = u * p;
        ns = u * g;
        float u0 = user_w[(long)iu * D + lane];
        float p0 = item_w[(long)ip * D + lane];
        float n0 = item_w[(long)in_ * D + lane];
        r = u0 * u0 + p0 * p0 + n0 * n0;
    }
#pragma unroll
    for (int off = 32; off; off >>= 1) {
        ps += __shfl_down(ps, off, 64);
        ns += __shfl_down(ns, off, 64);
        r  += __shfl_down(r, off, 64);
    }
    if (lane == 0) pr[threadIdx.x >> 6] = r;
    __syncthreads();
    if (threadIdx.x == 0)
        red[blockIdx.x] = pr[0] + pr[1] + pr[2] + pr[3];
    if (valid && lane == 0) {
        out[w] = ps;
        out[B_ + w] = ns;
    }
}

// single block: sum nblk partials -> out[2B]
__global__ void reduce_kernel(const float* __restrict__ red,
                              float* __restrict__ out_scalar, int nblk) {
    __shared__ float sh[256];
    float s = 0.f;
    for (int i = threadIdx.x; i < nblk; i += 256) s += red[i];
    sh[threadIdx.x] = s;
    __syncthreads();
    for (int off = 128; off; off >>= 1) {
        if (threadIdx.x < off) sh[threadIdx.x] += sh[threadIdx.x + off];
        __syncthreads();
    }
    if (threadIdx.x == 0) *out_scalar = sh[0];
}

// ---------------- launch ----------------
extern "C" void kernel_launch(void* const* d_in, const int* in_sizes, int n_in,
                              void* d_out, int out_size, void* d_ws, size_t ws_size,
                              hipStream_t stream) {
    const int*   edge_src = (const int*)d_in[0];
    const int*   edge_dst = (const int*)d_in[1];
    const float* edge_val = (const float*)d_in[2];
    const float* user_w   = (const float*)d_in[3];
    const float* item_w   = (const float*)d_in[4];
    const int*   bu       = (const int*)d_in[5];
    const int*   bp       = (const int*)d_in[6];
    const int*   bn       = (const int*)d_in[7];

    int E_ = in_sizes[0];
    int U_ = in_sizes[3] / D;
    int I_ = in_sizes[4] / D;
    int B_ = in_sizes[5];
    int N_ = U_ + I_;
    long ND = (long)N_ * D;
    int K_ = (N_ + 511) >> 9;   // dst buckets of 512 nodes (K_ <= 512 assumed)

    // ---- workspace layout ----
    char* p = (char*)d_ws;
    int2* col_val  = (int2*)p;       p += (size_t)E_ * sizeof(int2);
    int*  row_ptr  = (int*)p;        p += (size_t)(N_ + 1) * sizeof(int);
    int*  bkt_cnt  = (int*)p;        p += 512 * sizeof(int);
    int*  bkt_base = (int*)p;        p += 513 * sizeof(int);
    int*  g_pos    = (int*)p;        p += 512 * sizeof(int);
    float* red     = (float*)p;      p += 4096 * sizeof(float);
    p = (char*)(((uintptr_t)p + 255) & ~(uintptr_t)255);
    // overlay: staged edges (build phase) then embeddings (compute phase)
    int2* st = (int2*)p;
    float* acc = (float*)p;
    unsigned short* curb = (unsigned short*)(acc + ND);
    unsigned short* nxtb = curb + ND;
    float* out = (float*)d_out;

    int n4 = (int)(ND / 4);
    int nu4 = U_ * D / 4;

    // ---- CSR build ----
    hipMemsetAsync(bkt_cnt, 0, 512 * sizeof(int), stream);
    count_kernel<<<(E_ + 256 * EPTC - 1) / (256 * EPTC), 256, 0, stream>>>(
        edge_dst, bkt_cnt, K_, E_);
    scan_bkt_kernel<<<1, 512, 0, stream>>>(bkt_cnt, bkt_base, g_pos, K_, E_);
    partition_kernel<<<(E_ + 256 * EPT - 1) / (256 * EPT), 256, 0, stream>>>(
        edge_src, edge_dst, edge_val, g_pos, st, K_, E_);
    place_kernel<<<K_, 1024, 0, stream>>>(st, bkt_base, row_ptr, col_val,
                                          K_, N_, E_);

    // ---- embeddings init (overwrites staged region; stream-ordered) ----
    init_kernel<<<(n4 + 255) / 256, 256, 0, stream>>>(
        (const float4*)user_w, (const float4*)item_w,
        (float4*)acc, (ushort4*)curb, nu4, n4);

    // ---- propagation ----
    unsigned short* cb = curb;
    unsigned short* nb = nxtb;
    for (int l = 0; l < 3; ++l) {
        spmm_csr_kernel<<<(N_ + 3) / 4, 256, 0, stream>>>(
            row_ptr, col_val, (const uint4*)cb, (uint4*)nb, (float4*)acc,
            N_, (l < 2) ? 1 : 0);
        unsigned short* t = cb; cb = nb; nb = t;
    }

    // ---- epilogue ----
    int nblk = (B_ * 64 + 255) / 256;
    final_kernel<<<nblk, 256, 0, stream>>>(
        acc, user_w, item_w, bu, bp, bn, out, red, U_, B_);
    reduce_kernel<<<1, 256, 0, stream>>>(red, out + 2 * B_, nblk);
}